// Round 1
// baseline (499.410 us; speedup 1.0000x reference)
//
#include <hip/hip_runtime.h>
#include <stdint.h>

#define DIM 4096
#define NH 32
#define NKV 8
#define HD 128
#define SEQ 2048
#define KVD 1024  // NKV*HD

typedef unsigned short u16;
typedef __attribute__((ext_vector_type(8))) short bf16x8;   // 8 bf16 in 4 VGPRs
typedef __attribute__((ext_vector_type(4))) float f32x4;

__device__ __forceinline__ float bf2f(u16 v){
  union { unsigned u; float f; } c; c.u = ((unsigned)v) << 16; return c.f;
}
__device__ __forceinline__ u16 f2bf(float f){
  union { float f; unsigned u; } c; c.f = f;
  unsigned u = c.u;
  u += 0x7FFF + ((u >> 16) & 1);   // RNE
  return (u16)(u >> 16);
}

__device__ __forceinline__ void gl_lds16(const void* g, void* l){
  __builtin_amdgcn_global_load_lds((const __attribute__((address_space(1))) void*)g,
                                   (__attribute__((address_space(3))) void*)l, 16, 0, 0);
}

// ---------------- fp32 -> bf16 conversion (exact grids, sizes % 1024 == 0) ----
__global__ void cvt_bf16(const float* __restrict__ in, u16* __restrict__ out, int n){
  int i = (blockIdx.x*256 + threadIdx.x)*4;
  if (i + 3 >= n && i >= n) return;
  float4 v = *(const float4*)(in + i);
  ushort4 o;
  o.x = f2bf(v.x); o.y = f2bf(v.y); o.z = f2bf(v.z); o.w = f2bf(v.w);
  *(ushort4*)(out + i) = o;
}

// ---------------- NT GEMM: C[M,N] = A[M,K] * B[N,K]^T, bf16 in, bf16/f32 out --
// 128x128 tile, BK=64, 4 waves, 16x16x32 MFMA, global_load_lds(16B) staging,
// XOR swizzle (T2, both-sides: pre-swizzled global source + swizzled LDS read).
template<int OUTF32>
__global__ __launch_bounds__(256) void gemm_nt(const u16* __restrict__ A,
                                               const u16* __restrict__ B,
                                               void* __restrict__ C,
                                               const u16* __restrict__ B2,
                                               void* __restrict__ C2,
                                               int M, int N, int K){
  if (blockIdx.y){ B = B2; C = C2; }   // dual launch (K and V projections)
  __shared__ bf16x8 smA[128*8];   // [128 rows][8 slots of 8 bf16] = 16 KB
  __shared__ bf16x8 smB[128*8];
  const int t = threadIdx.x;
  const int w = t >> 6, l = t & 63;
  const int lg = l >> 4, li = l & 15;
  const int nbn = N >> 7;
  const int bm = blockIdx.x / nbn, bn = blockIdx.x % nbn;
  const int wr = w >> 1, wc = w & 1;

  f32x4 acc[4][4] = {};

  const int srow = t >> 3;    // staging: row within 32-row chunk
  const int sslot = t & 7;    // staging: 16B slot within 128B row

  for (int k0 = 0; k0 < K; k0 += 64){
    __syncthreads();
    #pragma unroll
    for (int j = 0; j < 4; ++j){
      const int row = j*32 + srow;
      const int scol = ((sslot ^ (row & 7)) << 3);  // swizzled source column (elems)
      gl_lds16(A + (size_t)(bm*128 + row)*K + k0 + scol, (char*)smA + j*4096 + w*1024);
      gl_lds16(B + (size_t)(bn*128 + row)*K + k0 + scol, (char*)smB + j*4096 + w*1024);
    }
    __syncthreads();
    #pragma unroll
    for (int kk = 0; kk < 2; ++kk){
      bf16x8 af[4], bfr[4];
      #pragma unroll
      for (int mi = 0; mi < 4; ++mi){
        const int Ra = wr*64 + mi*16 + li;
        af[mi]  = smA[Ra*8 + ((lg + 4*kk) ^ (Ra & 7))];
        const int Rb = wc*64 + mi*16 + li;
        bfr[mi] = smB[Rb*8 + ((lg + 4*kk) ^ (Rb & 7))];
      }
      #pragma unroll
      for (int mi = 0; mi < 4; ++mi)
        #pragma unroll
        for (int ni = 0; ni < 4; ++ni)
          acc[mi][ni] = __builtin_amdgcn_mfma_f32_16x16x32_bf16(af[mi], bfr[ni], acc[mi][ni], 0, 0, 0);
    }
  }
  #pragma unroll
  for (int mi = 0; mi < 4; ++mi)
    #pragma unroll
    for (int ni = 0; ni < 4; ++ni)
      #pragma unroll
      for (int r = 0; r < 4; ++r){
        const int row = bm*128 + wr*64 + mi*16 + lg*4 + r;
        const int col = bn*128 + wc*64 + ni*16 + li;
        if (OUTF32) ((float*)C)[(size_t)row*N + col] = acc[mi][ni][r];
        else        ((u16*)C)[(size_t)row*N + col]  = f2bf(acc[mi][ni][r]);
      }
}

// ---------------- RoPE (interleaved-pair convention, in place on bf16) -------
__global__ void rope_apply(u16* __restrict__ X, const float* __restrict__ rf, int nheads){
  const int idx = blockIdx.x*256 + threadIdx.x;
  const int i = idx & 63;
  const int h = (idx >> 6) % nheads;
  const int s = idx / (64*nheads);
  if (s >= SEQ) return;
  u16* p = X + (size_t)s*nheads*HD + h*HD + 2*i;
  const float c  = rf[s*256 + 4*i];
  const float sn = rf[s*256 + 4*i + 1];
  const float x0 = bf2f(p[0]), x1 = bf2f(p[1]);
  p[0] = f2bf(x0*c - x1*sn);
  p[1] = f2bf(x1*c + x0*sn);
}

// ---------------- 64x64-tile transpose: in[R][C] -> out[C][R] (bf16) ---------
__global__ __launch_bounds__(256) void transpose2d(const u16* __restrict__ in, u16* __restrict__ out,
                                                   int R, int Ccols){
  __shared__ u16 tile[64][65];
  const int t = threadIdx.x;
  const int bc = blockIdx.x, br = blockIdx.y;
  #pragma unroll
  for (int pass = 0; pass < 2; ++pass){
    const int r = (t >> 3) + pass*32;
    const int c0 = (t & 7)*8;
    const u16* src = in + (size_t)(br*64 + r)*Ccols + bc*64 + c0;
    #pragma unroll
    for (int j = 0; j < 8; ++j) tile[r][c0 + j] = src[j];
  }
  __syncthreads();
  #pragma unroll
  for (int pass = 0; pass < 2; ++pass){
    const int a = (t >> 3) + pass*32;
    const int c0 = (t & 7)*8;
    u16* dst = out + (size_t)(bc*64 + a)*R + br*64 + c0;
    #pragma unroll
    for (int j = 0; j < 8; ++j) dst[j] = tile[c0 + j][a];
  }
}

// ---------------- causal GQA flash attention ---------------------------------
// grid (qt = S/64, head). 4 waves; wave w owns q rows [qt*64+16w, +16).
// K tile [64][128] and Vt tile [128][64] staged via swizzled global_load_lds.
__global__ __launch_bounds__(256) void flash_attn(const u16* __restrict__ Q,
                                                  const u16* __restrict__ Kg,
                                                  const u16* __restrict__ Vt,
                                                  u16* __restrict__ O){
  __shared__ bf16x8 smK[64*16];               // [64 rows][16 slots] = 16 KB (swizzled)
  __shared__ bf16x8 smV[128*8];               // [128 rows][8 slots] = 16 KB (swizzled)
  __shared__ __align__(16) u16 smP[4][16*72]; // per-wave P tile, rows padded to 72
  const int qt = blockIdx.x, h = blockIdx.y, g = h >> 2;
  const int t = threadIdx.x, w = t >> 6, l = t & 63;
  const int lg = l >> 4, li = l & 15;

  bf16x8 qf[4];                                // Q row li, K-chunks (held all kernel)
  {
    const u16* qrow = Q + (size_t)(qt*64 + w*16 + li)*DIM + h*HD;
    #pragma unroll
    for (int kc = 0; kc < 4; ++kc)
      qf[kc] = *(const bf16x8*)(qrow + kc*32 + lg*8);
  }
  f32x4 accO[8] = {};
  float mrow[4] = {-1e30f,-1e30f,-1e30f,-1e30f};
  float lrow[4] = {0.f,0.f,0.f,0.f};
  const float scale = 0.08838834764831845f;   // 1/sqrt(128)

  const int ksrow = t >> 4, ksslot = t & 15;  // K staging: 256B rows, 16 slots
  const int vsrow = t >> 3, vsslot = t & 7;   // V staging: 128B rows, 8 slots

  for (int kt = 0; kt <= qt; ++kt){
    #pragma unroll
    for (int j = 0; j < 4; ++j){
      const int krow = j*16 + ksrow;
      const int ksl = (ksslot & 8) | ((ksslot ^ (krow & 7)) & 7);
      gl_lds16(Kg + (size_t)(kt*64 + krow)*KVD + g*HD + ksl*8, (char*)smK + j*4096 + w*1024);
      const int vrow = j*32 + vsrow;
      const int vsl = (vsslot ^ (vrow & 7)) & 7;
      gl_lds16(Vt + (size_t)(g*HD + vrow)*SEQ + kt*64 + vsl*8, (char*)smV + j*4096 + w*1024);
    }
    __syncthreads();
    // S = Q K^T  (D layout: row q = lg*4+r, col kv = nj*16+li)
    f32x4 sacc[4] = {};
    #pragma unroll
    for (int kc = 0; kc < 4; ++kc){
      #pragma unroll
      for (int nj = 0; nj < 4; ++nj){
        const int R = nj*16 + li;
        int sl = lg + 4*kc;
        sl = (sl & 8) | ((sl ^ (R & 7)) & 7);
        const bf16x8 kf = smK[R*16 + sl];
        sacc[nj] = __builtin_amdgcn_mfma_f32_16x16x32_bf16(qf[kc], kf, sacc[nj], 0, 0, 0);
      }
    }
    const int qbase = qt*64 + w*16 + lg*4;
    const int kbase = kt*64 + li;
    float p[4][4];
    #pragma unroll
    for (int nj = 0; nj < 4; ++nj)
      #pragma unroll
      for (int r = 0; r < 4; ++r){
        const float s = sacc[nj][r] * scale;
        p[nj][r] = (kbase + nj*16 <= qbase + r) ? s : -1e30f;
      }
    // online softmax: row spread over 16 lanes (li) x 4 frags (nj)
    #pragma unroll
    for (int r = 0; r < 4; ++r){
      float mx = fmaxf(fmaxf(p[0][r], p[1][r]), fmaxf(p[2][r], p[3][r]));
      mx = fmaxf(mx, __shfl_xor(mx, 1));
      mx = fmaxf(mx, __shfl_xor(mx, 2));
      mx = fmaxf(mx, __shfl_xor(mx, 4));
      mx = fmaxf(mx, __shfl_xor(mx, 8));
      const float mnew = fmaxf(mrow[r], mx);
      const float alpha = __expf(mrow[r] - mnew);
      float sum = 0.f;
      #pragma unroll
      for (int nj = 0; nj < 4; ++nj){ p[nj][r] = __expf(p[nj][r] - mnew); sum += p[nj][r]; }
      sum += __shfl_xor(sum, 1); sum += __shfl_xor(sum, 2);
      sum += __shfl_xor(sum, 4); sum += __shfl_xor(sum, 8);
      lrow[r] = lrow[r]*alpha + sum;
      mrow[r] = mnew;
      #pragma unroll
      for (int dj = 0; dj < 8; ++dj) accO[dj][r] *= alpha;
    }
    // restage P (per-wave region; same-wave ds ordering handled by compiler)
    u16* pw = smP[w];
    #pragma unroll
    for (int nj = 0; nj < 4; ++nj)
      #pragma unroll
      for (int r = 0; r < 4; ++r)
        pw[(lg*4 + r)*72 + nj*16 + li] = f2bf(p[nj][r]);
    // O += P V   (A-frag: P row li; B-frag: Vt row d)
    #pragma unroll
    for (int kc2 = 0; kc2 < 2; ++kc2){
      const bf16x8 pf = *(const bf16x8*)(pw + li*72 + kc2*32 + lg*8);
      #pragma unroll
      for (int dj = 0; dj < 8; ++dj){
        const int R = dj*16 + li;
        const bf16x8 vf = smV[R*8 + ((lg + 4*kc2) ^ (R & 7))];
        accO[dj] = __builtin_amdgcn_mfma_f32_16x16x32_bf16(pf, vf, accO[dj], 0, 0, 0);
      }
    }
    __syncthreads();   // protect smK/smV/smP from next-tile staging
  }
  #pragma unroll
  for (int dj = 0; dj < 8; ++dj)
    #pragma unroll
    for (int r = 0; r < 4; ++r){
      const float o = accO[dj][r] / lrow[r];
      O[(size_t)(qt*64 + w*16 + lg*4 + r)*DIM + h*HD + dj*16 + li] = f2bf(o);
    }
}

// -----------------------------------------------------------------------------
extern "C" void kernel_launch(void* const* d_in, const int* in_sizes, int n_in,
                              void* d_out, int out_size, void* d_ws, size_t ws_size,
                              hipStream_t stream){
  const float* x  = (const float*)d_in[0];
  const float* wq = (const float*)d_in[1];
  const float* wk = (const float*)d_in[2];
  const float* wv = (const float*)d_in[3];
  const float* wo = (const float*)d_in[4];
  const float* rf = (const float*)d_in[5];
  // d_in[6] = start_pos (unused by the reference)
  float* out = (float*)d_out;

  char* ws = (char*)d_ws;
  size_t off = 0;
  auto alloc = [&](size_t nbytes){ void* p = ws + off; off += (nbytes + 255) & ~(size_t)255; return p; };
  u16* xb  = (u16*)alloc((size_t)SEQ*DIM*2);
  u16* wqb = (u16*)alloc((size_t)DIM*DIM*2);
  u16* wkb = (u16*)alloc((size_t)KVD*DIM*2);
  u16* wvb = (u16*)alloc((size_t)KVD*DIM*2);
  u16* wob = (u16*)alloc((size_t)DIM*DIM*2);
  u16* Qb  = (u16*)alloc((size_t)SEQ*DIM*2);
  u16* K8  = (u16*)alloc((size_t)SEQ*KVD*2);
  u16* V8  = (u16*)alloc((size_t)SEQ*KVD*2);
  u16* Vtr = (u16*)alloc((size_t)KVD*SEQ*2);
  u16* AO  = (u16*)alloc((size_t)SEQ*DIM*2);

  cvt_bf16<<<SEQ*DIM/1024, 256, 0, stream>>>(x,  xb,  SEQ*DIM);
  cvt_bf16<<<DIM*DIM/1024, 256, 0, stream>>>(wq, wqb, DIM*DIM);
  cvt_bf16<<<KVD*DIM/1024, 256, 0, stream>>>(wk, wkb, KVD*DIM);
  cvt_bf16<<<KVD*DIM/1024, 256, 0, stream>>>(wv, wvb, KVD*DIM);
  cvt_bf16<<<DIM*DIM/1024, 256, 0, stream>>>(wo, wob, DIM*DIM);

  // Q projection (512 blocks); K and V projections dual-launched (256 blocks)
  gemm_nt<0><<<dim3((SEQ/128)*(DIM/128), 1), 256, 0, stream>>>(xb, wqb, Qb, nullptr, nullptr, SEQ, DIM, DIM);
  gemm_nt<0><<<dim3((SEQ/128)*(KVD/128), 2), 256, 0, stream>>>(xb, wkb, K8, wvb, V8, SEQ, KVD, DIM);

  rope_apply<<<SEQ*NH*64/256,  256, 0, stream>>>(Qb, rf, NH);
  rope_apply<<<SEQ*NKV*64/256, 256, 0, stream>>>(K8, rf, NKV);

  transpose2d<<<dim3(KVD/64, SEQ/64), 256, 0, stream>>>(V8, Vtr, SEQ, KVD);

  flash_attn<<<dim3(SEQ/64, NH), 256, 0, stream>>>(Qb, K8, Vtr, AO);

  gemm_nt<1><<<dim3((SEQ/128)*(DIM/128), 1), 256, 0, stream>>>(AO, wob, out, nullptr, nullptr, SEQ, DIM, DIM);
}

// Round 2
// 394.292 us; speedup vs baseline: 1.2666x; 1.2666x over previous
//
#include <hip/hip_runtime.h>
#include <stdint.h>

#define DIM 4096
#define NH 32
#define NKV 8
#define HD 128
#define SEQ 2048
#define KVD 1024  // NKV*HD

typedef unsigned short u16;
typedef __attribute__((ext_vector_type(8))) short bf16x8;   // 8 bf16 in 4 VGPRs
typedef __attribute__((ext_vector_type(4))) float f32x4;

__device__ __forceinline__ float bf2f(u16 v){
  union { unsigned u; float f; } c; c.u = ((unsigned)v) << 16; return c.f;
}
__device__ __forceinline__ u16 f2bf(float f){
  union { float f; unsigned u; } c; c.f = f;
  unsigned u = c.u;
  u += 0x7FFF + ((u >> 16) & 1);   // RNE
  return (u16)(u >> 16);
}
__device__ __forceinline__ unsigned pack2bf(float a, float b){
  return (unsigned)f2bf(a) | ((unsigned)f2bf(b) << 16);
}

__device__ __forceinline__ void gl_lds16(const void* g, void* l){
  __builtin_amdgcn_global_load_lds((const __attribute__((address_space(1))) void*)g,
                                   (__attribute__((address_space(3))) void*)l, 16, 0, 0);
}

// ---------------- fp32 -> bf16 conversion (exact grids, sizes % 1024 == 0) ----
__global__ void cvt_bf16(const float* __restrict__ in, u16* __restrict__ out, int n){
  int i = (blockIdx.x*256 + threadIdx.x)*4;
  if (i + 3 >= n && i >= n) return;
  float4 v = *(const float4*)(in + i);
  ushort4 o;
  o.x = f2bf(v.x); o.y = f2bf(v.y); o.z = f2bf(v.z); o.w = f2bf(v.w);
  *(ushort4*)(out + i) = o;
}

// ---------------- NT GEMM: C[M,N] = A[M,K] * B[N,K]^T, bf16 in, bf16/f32 out --
// 128x128 tile, BK=64, 4 waves, 16x16x32 MFMA, global_load_lds(16B) staging,
// XOR swizzle (T2 both-sides), XCD-aware blockIdx swizzle (T1).
template<int OUTF32>
__global__ __launch_bounds__(256) void gemm_nt(const u16* __restrict__ A,
                                               const u16* __restrict__ B,
                                               void* __restrict__ C,
                                               const u16* __restrict__ B2,
                                               void* __restrict__ C2,
                                               int M, int N, int K){
  if (blockIdx.y){ B = B2; C = C2; }   // dual launch (K and V projections)
  __shared__ bf16x8 smA[128*8];   // [128 rows][8 slots of 8 bf16] = 16 KB
  __shared__ bf16x8 smB[128*8];
  const int t = threadIdx.x;
  const int w = t >> 6, l = t & 63;
  const int lg = l >> 4, li = l & 15;
  const int nbn = N >> 7;
  // XCD swizzle (gridDim.x % 8 == 0 for all our launches)
  const int nbx = gridDim.x;
  const int bid = (blockIdx.x & 7) * (nbx >> 3) + (blockIdx.x >> 3);
  const int bm = bid / nbn, bn = bid % nbn;
  const int wr = w >> 1, wc = w & 1;

  f32x4 acc[4][4] = {};

  const int srow = t >> 3;    // staging: row within 32-row chunk
  const int sslot = t & 7;    // staging: 16B slot within 128B row

  for (int k0 = 0; k0 < K; k0 += 64){
    __syncthreads();
    #pragma unroll
    for (int j = 0; j < 4; ++j){
      const int row = j*32 + srow;
      const int scol = ((sslot ^ (row & 7)) << 3);  // swizzled source column (elems)
      gl_lds16(A + (size_t)(bm*128 + row)*K + k0 + scol, (char*)smA + j*4096 + w*1024);
      gl_lds16(B + (size_t)(bn*128 + row)*K + k0 + scol, (char*)smB + j*4096 + w*1024);
    }
    __syncthreads();
    #pragma unroll
    for (int kk = 0; kk < 2; ++kk){
      bf16x8 af[4], bfr[4];
      #pragma unroll
      for (int mi = 0; mi < 4; ++mi){
        const int Ra = wr*64 + mi*16 + li;
        af[mi]  = smA[Ra*8 + ((lg + 4*kk) ^ (Ra & 7))];
        const int Rb = wc*64 + mi*16 + li;
        bfr[mi] = smB[Rb*8 + ((lg + 4*kk) ^ (Rb & 7))];
      }
      #pragma unroll
      for (int mi = 0; mi < 4; ++mi)
        #pragma unroll
        for (int ni = 0; ni < 4; ++ni)
          acc[mi][ni] = __builtin_amdgcn_mfma_f32_16x16x32_bf16(af[mi], bfr[ni], acc[mi][ni], 0, 0, 0);
    }
  }
  #pragma unroll
  for (int mi = 0; mi < 4; ++mi)
    #pragma unroll
    for (int ni = 0; ni < 4; ++ni)
      #pragma unroll
      for (int r = 0; r < 4; ++r){
        const int row = bm*128 + wr*64 + mi*16 + lg*4 + r;
        const int col = bn*128 + wc*64 + ni*16 + li;
        if (OUTF32) ((float*)C)[(size_t)row*N + col] = acc[mi][ni][r];
        else        ((u16*)C)[(size_t)row*N + col]  = f2bf(acc[mi][ni][r]);
      }
}

// ---------------- RoPE (interleaved-pair convention, in place on bf16) -------
__global__ void rope_apply(u16* __restrict__ X, const float* __restrict__ rf, int nheads){
  const int idx = blockIdx.x*256 + threadIdx.x;
  const int i = idx & 63;
  const int h = (idx >> 6) % nheads;
  const int s = idx / (64*nheads);
  if (s >= SEQ) return;
  u16* p = X + (size_t)s*nheads*HD + h*HD + 2*i;
  const float c  = rf[s*256 + 4*i];
  const float sn = rf[s*256 + 4*i + 1];
  const float x0 = bf2f(p[0]), x1 = bf2f(p[1]);
  p[0] = f2bf(x0*c - x1*sn);
  p[1] = f2bf(x1*c + x0*sn);
}

// ---------------- 64x64-tile transpose: in[R][C] -> out[C][R] (bf16) ---------
__global__ __launch_bounds__(256) void transpose2d(const u16* __restrict__ in, u16* __restrict__ out,
                                                   int R, int Ccols){
  __shared__ u16 tile[64][65];
  const int t = threadIdx.x;
  const int bc = blockIdx.x, br = blockIdx.y;
  #pragma unroll
  for (int pass = 0; pass < 2; ++pass){
    const int r = (t >> 3) + pass*32;
    const int c0 = (t & 7)*8;
    const u16* src = in + (size_t)(br*64 + r)*Ccols + bc*64 + c0;
    #pragma unroll
    for (int j = 0; j < 8; ++j) tile[r][c0 + j] = src[j];
  }
  __syncthreads();
  #pragma unroll
  for (int pass = 0; pass < 2; ++pass){
    const int a = (t >> 3) + pass*32;
    const int c0 = (t & 7)*8;
    u16* dst = out + (size_t)(bc*64 + a)*R + br*64 + c0;
    #pragma unroll
    for (int j = 0; j < 8; ++j) dst[j] = tile[c0 + j][a];
  }
}

// ---------------- causal GQA flash attention ---------------------------------
// 1D grid 1024, longest-qt blocks first: qt = 31 - bid/32, h = bid%32.
// 4 waves; wave w owns q rows [qt*64+16w, +16). Swapped QK^T (mfma(K,Q)) so
// each lane owns one full q-row (q = li): in-lane softmax + 2-shfl reduce.
// K/V double-buffered in LDS, next tile staged before compute (2-phase T3).
__global__ __launch_bounds__(256) void flash_attn(const u16* __restrict__ Q,
                                                  const u16* __restrict__ Kg,
                                                  const u16* __restrict__ Vt,
                                                  u16* __restrict__ O){
  __shared__ bf16x8 smK[2][64*16];              // [64 rows][16 slots], swizzled; 2x16KB
  __shared__ bf16x8 smV[2][128*8];              // [128 rows][8 slots], swizzled; 2x16KB
  __shared__ __align__(16) u16 smP[4][16*64];   // per-wave P, XOR-swizzled 16B chunks; 8KB
  const int bid = blockIdx.x;
  const int h  = bid & 31;
  const int qt = 31 - (bid >> 5);
  const int g  = h >> 2;
  const int t = threadIdx.x, w = t >> 6, l = t & 63;
  const int lg = l >> 4, li = l & 15;

  bf16x8 qf[4];                                  // Q row (w*16+li), d-chunks
  {
    const u16* qrow = Q + (size_t)(qt*64 + w*16 + li)*DIM + h*HD;
    #pragma unroll
    for (int kc = 0; kc < 4; ++kc)
      qf[kc] = *(const bf16x8*)(qrow + kc*32 + lg*8);
  }
  f32x4 accO[8] = {};
  float mrun = -1e30f, lsum = 0.f;
  const float SC = 0.08838834764831845f * 1.4426950408889634f;  // scale * log2(e)

  const int ksrow = t >> 4, ksslot = t & 15;  // K staging: 256B rows, 16 slots
  const int vsrow = t >> 3, vsslot = t & 7;   // V staging: 128B rows, 8 slots

  auto stage = [&](int kt, int b){
    #pragma unroll
    for (int j = 0; j < 4; ++j){
      const int krow = j*16 + ksrow;
      const int ksl = (ksslot & 8) | ((ksslot ^ (krow & 7)) & 7);
      gl_lds16(Kg + (size_t)(kt*64 + krow)*KVD + g*HD + ksl*8, (char*)&smK[b][0] + j*4096 + w*1024);
      const int vrow = j*32 + vsrow;
      const int vsl = (vsslot ^ (vrow & 7)) & 7;
      gl_lds16(Vt + (size_t)(g*HD + vrow)*SEQ + kt*64 + vsl*8, (char*)&smV[b][0] + j*4096 + w*1024);
    }
  };

  stage(0, 0);
  int buf = 0;
  u16* pw = &smP[w][0];

  for (int kt = 0; kt <= qt; ++kt){
    __syncthreads();                      // implicit vmcnt(0): tile-kt stage done
    if (kt < qt) stage(kt + 1, buf ^ 1);  // overlap next stage with this compute

    // S^T = K Q^T : lane holds S[kk = nj*16+lg*4+r][q = li]
    f32x4 sacc[4] = {};
    #pragma unroll
    for (int kc = 0; kc < 4; ++kc){
      #pragma unroll
      for (int nj = 0; nj < 4; ++nj){
        const int R = nj*16 + li;
        int sl = lg + 4*kc;
        sl = (sl & 8) | ((sl ^ (R & 7)) & 7);
        sacc[nj] = __builtin_amdgcn_mfma_f32_16x16x32_bf16(smK[buf][R*16 + sl], qf[kc], sacc[nj], 0, 0, 0);
      }
    }
    float p[4][4];
    #pragma unroll
    for (int nj = 0; nj < 4; ++nj)
      #pragma unroll
      for (int r = 0; r < 4; ++r)
        p[nj][r] = sacc[nj][r] * SC;
    if (kt == qt){                         // mask only on the diagonal tile
      const int qloc = w*16 + li;
      #pragma unroll
      for (int nj = 0; nj < 4; ++nj)
        #pragma unroll
        for (int r = 0; r < 4; ++r)
          if (nj*16 + lg*4 + r > qloc) p[nj][r] = -1e30f;
    }
    // online softmax, row q=li fully in this lane (16 vals) + lanes l^16,l^32
    float mx = p[0][0];
    #pragma unroll
    for (int nj = 0; nj < 4; ++nj)
      #pragma unroll
      for (int r = 0; r < 4; ++r) mx = fmaxf(mx, p[nj][r]);
    mx = fmaxf(mx, __shfl_xor(mx, 16));
    mx = fmaxf(mx, __shfl_xor(mx, 32));
    const float mnew = fmaxf(mrun, mx);
    const float alpha = exp2f(mrun - mnew);
    float s = 0.f;
    #pragma unroll
    for (int nj = 0; nj < 4; ++nj)
      #pragma unroll
      for (int r = 0; r < 4; ++r){ p[nj][r] = exp2f(p[nj][r] - mnew); s += p[nj][r]; }
    s += __shfl_xor(s, 16);
    s += __shfl_xor(s, 32);
    lsum = lsum * alpha + s;
    mrun = mnew;
    // broadcast alpha to accO's rows (q = lg*4+r held by lane li' = lg*4+r)
    float al[4];
    #pragma unroll
    for (int r = 0; r < 4; ++r) al[r] = __shfl(alpha, (l & 48) | (lg*4 + r));
    #pragma unroll
    for (int dj = 0; dj < 8; ++dj)
      #pragma unroll
      for (int r = 0; r < 4; ++r) accO[dj][r] *= al[r];
    // write P (row q=li, kk consecutive per write): 4x 8B swizzled ds_write
    #pragma unroll
    for (int nj = 0; nj < 4; ++nj){
      const int c = nj*2 + (lg >> 1);
      uint2 v; v.x = pack2bf(p[nj][0], p[nj][1]); v.y = pack2bf(p[nj][2], p[nj][3]);
      *(uint2*)((char*)pw + li*128 + ((c ^ (li & 7)) << 4) + ((lg & 1) << 3)) = v;
    }
    // O += P V   (A-frag: P row li, kk = kc2*32+lg*8+j; B-frag: Vt row d)
    #pragma unroll
    for (int kc2 = 0; kc2 < 2; ++kc2){
      const bf16x8 pf = *(const bf16x8*)((char*)pw + li*128 + (((kc2*4 + lg) ^ (li & 7)) << 4));
      #pragma unroll
      for (int dj = 0; dj < 8; ++dj){
        const int R = dj*16 + li;
        const bf16x8 vf = smV[buf][R*8 + ((lg + 4*kc2) ^ (R & 7))];
        accO[dj] = __builtin_amdgcn_mfma_f32_16x16x32_bf16(pf, vf, accO[dj], 0, 0, 0);
      }
    }
    buf ^= 1;
  }
  // epilogue: divide by row sum (row q=lg*4+r), write
  float linv[4];
  #pragma unroll
  for (int r = 0; r < 4; ++r) linv[r] = 1.f / __shfl(lsum, (l & 48) | (lg*4 + r));
  #pragma unroll
  for (int dj = 0; dj < 8; ++dj)
    #pragma unroll
    for (int r = 0; r < 4; ++r)
      O[(size_t)(qt*64 + w*16 + lg*4 + r)*DIM + h*HD + dj*16 + li] = f2bf(accO[dj][r] * linv[r]);
}

// -----------------------------------------------------------------------------
extern "C" void kernel_launch(void* const* d_in, const int* in_sizes, int n_in,
                              void* d_out, int out_size, void* d_ws, size_t ws_size,
                              hipStream_t stream){
  const float* x  = (const float*)d_in[0];
  const float* wq = (const float*)d_in[1];
  const float* wk = (const float*)d_in[2];
  const float* wv = (const float*)d_in[3];
  const float* wo = (const float*)d_in[4];
  const float* rf = (const float*)d_in[5];
  // d_in[6] = start_pos (unused by the reference)
  float* out = (float*)d_out;

  char* ws = (char*)d_ws;
  size_t off = 0;
  auto alloc = [&](size_t nbytes){ void* p = ws + off; off += (nbytes + 255) & ~(size_t)255; return p; };
  u16* xb  = (u16*)alloc((size_t)SEQ*DIM*2);
  u16* wqb = (u16*)alloc((size_t)DIM*DIM*2);
  u16* wkb = (u16*)alloc((size_t)KVD*DIM*2);
  u16* wvb = (u16*)alloc((size_t)KVD*DIM*2);
  u16* wob = (u16*)alloc((size_t)DIM*DIM*2);
  u16* Qb  = (u16*)alloc((size_t)SEQ*DIM*2);
  u16* K8  = (u16*)alloc((size_t)SEQ*KVD*2);
  u16* V8  = (u16*)alloc((size_t)SEQ*KVD*2);
  u16* Vtr = (u16*)alloc((size_t)KVD*SEQ*2);
  u16* AO  = (u16*)alloc((size_t)SEQ*DIM*2);

  cvt_bf16<<<SEQ*DIM/1024, 256, 0, stream>>>(x,  xb,  SEQ*DIM);
  cvt_bf16<<<DIM*DIM/1024, 256, 0, stream>>>(wq, wqb, DIM*DIM);
  cvt_bf16<<<KVD*DIM/1024, 256, 0, stream>>>(wk, wkb, KVD*DIM);
  cvt_bf16<<<KVD*DIM/1024, 256, 0, stream>>>(wv, wvb, KVD*DIM);
  cvt_bf16<<<DIM*DIM/1024, 256, 0, stream>>>(wo, wob, DIM*DIM);

  // Q projection (512 blocks); K and V projections dual-launched (256 blocks x2)
  gemm_nt<0><<<dim3((SEQ/128)*(DIM/128), 1), 256, 0, stream>>>(xb, wqb, Qb, nullptr, nullptr, SEQ, DIM, DIM);
  gemm_nt<0><<<dim3((SEQ/128)*(KVD/128), 2), 256, 0, stream>>>(xb, wkb, K8, wvb, V8, SEQ, KVD, DIM);

  rope_apply<<<SEQ*NH*64/256,  256, 0, stream>>>(Qb, rf, NH);
  rope_apply<<<SEQ*NKV*64/256, 256, 0, stream>>>(K8, rf, NKV);

  transpose2d<<<dim3(KVD/64, SEQ/64), 256, 0, stream>>>(V8, Vtr, SEQ, KVD);

  flash_attn<<<SEQ/64 * NH, 256, 0, stream>>>(Qb, K8, Vtr, AO);

  gemm_nt<1><<<dim3((SEQ/128)*(DIM/128), 1), 256, 0, stream>>>(AO, wob, out, nullptr, nullptr, SEQ, DIM, DIM);
}